// Round 6
// baseline (767.141 us; speedup 1.0000x reference)
//
#include <hip/hip_runtime.h>
#include <hip/hip_bf16.h>
#include <math.h>

#define HH 10
#define DD 256

// v = v + dpp_shuffled(v); full-rate VALU lane exchange within 16-lane rows.
template<int CTRL>
__device__ __forceinline__ float dpp_add(float v) {
  int t = __builtin_amdgcn_mov_dpp(__float_as_int(v), CTRL, 0xF, 0xF, true);
  return v + __int_as_float(t);
}

// All-lanes sum across the 64-lane wave.
// 4 DPP stages give every lane its 16-lane row sum (quad xor1, quad xor2,
// row_half_mirror, row_mirror are all involutions -> butterfly-valid),
// then 2 ds_bpermute-backed shuffles cross the 16/32 boundaries.
__device__ __forceinline__ float wave_sum64(float v) {
  v = dpp_add<0xB1>(v);    // quad_perm {1,0,3,2}  (xor 1)
  v = dpp_add<0x4E>(v);    // quad_perm {2,3,0,1}  (xor 2)
  v = dpp_add<0x141>(v);   // row_half_mirror      (8-block)
  v = dpp_add<0x140>(v);   // row_mirror           (16-block)
  v += __shfl_xor(v, 16, 64);
  v += __shfl_xor(v, 32, 64);
  return v;
}

// off[g] = first index with seg[i] >= g; off[G] = n. Handles empty segments.
__global__ void seg_offsets_kernel(const int* __restrict__ seg, int n, int G,
                                   int* __restrict__ off) {
  int i = blockIdx.x * blockDim.x + threadIdx.x;
  if (i >= n) return;
  int cur = seg[i];
  int prev = (i == 0) ? -1 : seg[i - 1];
  for (int g = prev + 1; g <= cur; ++g) off[g] = i;
  if (i == n - 1) {
    for (int g = cur + 1; g <= G; ++g) off[g] = n;
  }
}

// One wave64 per segment. Lane owns columns d = lane*4 .. lane*4+3.
__global__ __launch_bounds__(256) void seg_pool_kernel(
    const float* __restrict__ feat, const float* __restrict__ W,
    const float* __restrict__ b, const int* __restrict__ off,
    float* __restrict__ out, int G) {
  const int lane = threadIdx.x & 63;
  const int g = blockIdx.x * 4 + (threadIdx.x >> 6);
  if (g >= G) return;

  // Per-lane W fragment: rows d = lane*4+j, all 10 heads. W is [256][10].
  float wreg[4][HH];
  {
    const float* wp = W + lane * 4 * HH;
#pragma unroll
    for (int j = 0; j < 4; ++j)
#pragma unroll
      for (int k = 0; k < HH; ++k) wreg[j][k] = wp[j * HH + k];
  }
  float bias[HH];
#pragma unroll
  for (int k = 0; k < HH; ++k) bias[k] = b[k];

  float acc[HH][4];
  float dsum[HH];
#pragma unroll
  for (int k = 0; k < HH; ++k) {
    dsum[k] = 0.f;
    acc[k][0] = acc[k][1] = acc[k][2] = acc[k][3] = 0.f;
  }

  const int s = off[g];
  const int e = off[g + 1];

  if (s < e) {
    const float* fp = feat + (size_t)s * DD + lane * 4;
    float4 f = *reinterpret_cast<const float4*>(fp);

    for (int n = s; n < e; ++n) {
      // Prefetch next node's row while we process this one.
      float4 fn;
      if (n + 1 < e)
        fn = *reinterpret_cast<const float4*>(fp + (size_t)(n + 1 - s) * DD);

      // Partial dot products for all 10 heads (this lane's 4 columns).
      float p[HH];
#pragma unroll
      for (int k = 0; k < HH; ++k) {
        float t = f.x * wreg[0][k];
        t = fmaf(f.y, wreg[1][k], t);
        t = fmaf(f.z, wreg[2][k], t);
        t = fmaf(f.w, wreg[3][k], t);
        p[k] = t;
      }
#pragma unroll
      for (int k = 0; k < HH; ++k) p[k] = wave_sum64(p[k]);

#pragma unroll
      for (int k = 0; k < HH; ++k) {
        float x = p[k] + bias[k];
        float wgt = __builtin_amdgcn_rcpf(1.f + __expf(-x));  // sigmoid
        dsum[k] += wgt;
        acc[k][0] = fmaf(wgt, f.x, acc[k][0]);
        acc[k][1] = fmaf(wgt, f.y, acc[k][1]);
        acc[k][2] = fmaf(wgt, f.z, acc[k][2]);
        acc[k][3] = fmaf(wgt, f.w, acc[k][3]);
      }

      f = fn;
    }
  }

  // keys[g][k][d] = num/denom ; 0/0 -> NaN matches reference on empty segs.
  float* op = out + ((size_t)g * HH) * DD + lane * 4;
#pragma unroll
  for (int k = 0; k < HH; ++k) {
    float r = __builtin_amdgcn_rcpf(dsum[k]);
    float4 o = make_float4(acc[k][0] * r, acc[k][1] * r,
                           acc[k][2] * r, acc[k][3] * r);
    *reinterpret_cast<float4*>(op + (size_t)k * DD) = o;
  }
}

extern "C" void kernel_launch(void* const* d_in, const int* in_sizes, int n_in,
                              void* d_out, int out_size, void* d_ws, size_t ws_size,
                              hipStream_t stream) {
  const float* feat = (const float*)d_in[0];
  const float* W    = (const float*)d_in[1];
  const float* b    = (const float*)d_in[2];
  const int*   seg  = (const int*)d_in[3];
  float* out = (float*)d_out;

  const int H_ = in_sizes[2];             // 10
  const int D_ = in_sizes[1] / H_;        // 256
  const int N  = in_sizes[0] / D_;        // 500000
  const int G  = out_size / (H_ * D_);    // 8192

  int* off = (int*)d_ws;                  // (G+1) ints of scratch

  seg_offsets_kernel<<<(N + 255) / 256, 256, 0, stream>>>(seg, N, G, off);
  seg_pool_kernel<<<(G + 3) / 4, 256, 0, stream>>>(feat, W, b, off, out, G);
}

// Round 8
// 748.336 us; speedup vs baseline: 1.0251x; 1.0251x over previous
//
#include <hip/hip_runtime.h>
#include <hip/hip_bf16.h>
#include <math.h>

#define HH 10
#define DD 256
#define WPS 4   // waves per segment (block = 256 threads = 4 waves)

// v = v + dpp_shuffled(v); full-rate VALU lane exchange within 16-lane rows.
template<int CTRL>
__device__ __forceinline__ float dpp_add(float v) {
  int t = __builtin_amdgcn_mov_dpp(__float_as_int(v), CTRL, 0xF, 0xF, true);
  return v + __int_as_float(t);
}

// All-lanes sum across the 64-lane wave (butterfly allreduce).
__device__ __forceinline__ float wave_sum64(float v) {
  v = dpp_add<0xB1>(v);    // quad_perm {1,0,3,2}  (xor 1)
  v = dpp_add<0x4E>(v);    // quad_perm {2,3,0,1}  (xor 2)
  v = dpp_add<0x141>(v);   // row_half_mirror      (8-block)
  v = dpp_add<0x140>(v);   // row_mirror           (16-block)
  v += __shfl_xor(v, 16, 64);
  v += __shfl_xor(v, 32, 64);
  return v;
}

// off[g] = first index with seg[i] >= g; off[G] = n. Handles empty segments.
__global__ void seg_offsets_kernel(const int* __restrict__ seg, int n, int G,
                                   int* __restrict__ off) {
  int i = blockIdx.x * blockDim.x + threadIdx.x;
  if (i >= n) return;
  int cur = seg[i];
  int prev = (i == 0) ? -1 : seg[i - 1];
  for (int g = prev + 1; g <= cur; ++g) off[g] = i;
  if (i == n - 1) {
    for (int g = cur + 1; g <= G; ++g) off[g] = n;
  }
}

// One block (4 waves) per segment. Wave w handles nodes s+w, s+w+4, ...
// Lane owns columns d = lane*4 .. lane*4+3. Partials combined via LDS.
__global__ __launch_bounds__(256) void seg_pool_kernel(
    const float* __restrict__ feat, const float* __restrict__ W,
    const float* __restrict__ b, const int* __restrict__ off,
    float* __restrict__ out) {
  const int lane = threadIdx.x & 63;
  const int wv = threadIdx.x >> 6;
  const int g = blockIdx.x;

  // Waves 1..3 park partials here; wave 0 keeps its own in registers.
  __shared__ float lacc[WPS - 1][64][HH * 4];  // 30 KB
  __shared__ float ldsum[WPS][HH];

  // Per-lane W fragment: rows d = lane*4+j, all 10 heads. W is [256][10].
  float wreg[4][HH];
  {
    const float* wp = W + lane * 4 * HH;
#pragma unroll
    for (int j = 0; j < 4; ++j)
#pragma unroll
      for (int k = 0; k < HH; ++k) wreg[j][k] = wp[j * HH + k];
  }
  float bias[HH];
#pragma unroll
  for (int k = 0; k < HH; ++k) bias[k] = b[k];

  float acc[HH][4];
  float dsum[HH];
#pragma unroll
  for (int k = 0; k < HH; ++k) {
    dsum[k] = 0.f;
    acc[k][0] = acc[k][1] = acc[k][2] = acc[k][3] = 0.f;
  }

  const int s = off[g];
  const int e = off[g + 1];
  const int m = e - s;
  const int cnt = (m > wv) ? ((m - wv + WPS - 1) >> 2) : 0;

  if (cnt > 0) {
    const int last = e - 1;
    // Clamped row pointer: overshooting prefetches re-read the last row
    // (never consumed as an extra node). Row index is wave-uniform -> SALU.
    auto rowp = [&](int i) {
      int idx = s + wv + (i << 2);
      if (idx > last) idx = last;
      return reinterpret_cast<const float4*>(feat + (size_t)idx * DD + lane * 4);
    };

    float4 f0 = *rowp(0);
    float4 f1 = *rowp(1);

    for (int i = 0; i < cnt; ++i) {
      float4 fn = *rowp(i + 2);   // 2-deep prefetch, always issued

      // Partial dot products for all 10 heads (this lane's 4 columns).
      float p[HH];
#pragma unroll
      for (int k = 0; k < HH; ++k) {
        float t = f0.x * wreg[0][k];
        t = fmaf(f0.y, wreg[1][k], t);
        t = fmaf(f0.z, wreg[2][k], t);
        t = fmaf(f0.w, wreg[3][k], t);
        p[k] = t;
      }
#pragma unroll
      for (int k = 0; k < HH; ++k) p[k] = wave_sum64(p[k]);

#pragma unroll
      for (int k = 0; k < HH; ++k) {
        float x = p[k] + bias[k];
        float wgt = __builtin_amdgcn_rcpf(1.f + __expf(-x));  // sigmoid
        dsum[k] += wgt;
        acc[k][0] = fmaf(wgt, f0.x, acc[k][0]);
        acc[k][1] = fmaf(wgt, f0.y, acc[k][1]);
        acc[k][2] = fmaf(wgt, f0.z, acc[k][2]);
        acc[k][3] = fmaf(wgt, f0.w, acc[k][3]);
      }

      f0 = f1;
      f1 = fn;
    }
  }

  // Park partials: waves 1..3 -> LDS; dsum is lane-uniform, lane 0 writes it.
  if (wv > 0) {
    float* lp = &lacc[wv - 1][lane][0];
#pragma unroll
    for (int k = 0; k < HH; ++k) {
      float4 v4 = make_float4(acc[k][0], acc[k][1], acc[k][2], acc[k][3]);
      *reinterpret_cast<float4*>(lp + k * 4) = v4;
    }
  }
  if (lane == 0) {
#pragma unroll
    for (int k = 0; k < HH; ++k) ldsum[wv][k] = dsum[k];
  }
  __syncthreads();

  if (wv == 0) {
    float* op = out + ((size_t)g * HH) * DD + lane * 4;
#pragma unroll
    for (int k = 0; k < HH; ++k) {
      float4 a = make_float4(acc[k][0], acc[k][1], acc[k][2], acc[k][3]);
#pragma unroll
      for (int w = 0; w < WPS - 1; ++w) {
        float4 t = *reinterpret_cast<const float4*>(&lacc[w][lane][k * 4]);
        a.x += t.x; a.y += t.y; a.z += t.z; a.w += t.w;
      }
      float ds = ldsum[0][k] + ldsum[1][k] + ldsum[2][k] + ldsum[3][k];
      float r = __builtin_amdgcn_rcpf(ds);   // 0/0 -> NaN matches reference
      float4 o = make_float4(a.x * r, a.y * r, a.z * r, a.w * r);
      *reinterpret_cast<float4*>(op + (size_t)k * DD) = o;
    }
  }
}

extern "C" void kernel_launch(void* const* d_in, const int* in_sizes, int n_in,
                              void* d_out, int out_size, void* d_ws, size_t ws_size,
                              hipStream_t stream) {
  const float* feat = (const float*)d_in[0];
  const float* W    = (const float*)d_in[1];
  const float* b    = (const float*)d_in[2];
  const int*   seg  = (const int*)d_in[3];
  float* out = (float*)d_out;

  const int H_ = in_sizes[2];             // 10
  const int D_ = in_sizes[1] / H_;        // 256
  const int N  = in_sizes[0] / D_;        // 500000
  const int G  = out_size / (H_ * D_);    // 8192

  int* off = (int*)d_ws;                  // (G+1) ints of scratch

  seg_offsets_kernel<<<(N + 255) / 256, 256, 0, stream>>>(seg, N, G, off);
  seg_pool_kernel<<<G, 256, 0, stream>>>(feat, W, b, off, out);
}